// Round 20
// baseline (156.768 us; speedup 1.0000x reference)
//
#include <hip/hip_runtime.h>
#include <math.h>

#define NEG_SLOPE 0.2f
#define PB 1024       // partition blocks (fixed chunking shared by hist/scatter)
#define BKT_SHIFT 8   // 256 nodes per bucket (R15-proven)
#define SCHUNK 8192   // hist entries per scan_a block
#define SSHIFT 13

typedef __attribute__((ext_vector_type(8))) short bf16x8;
typedef __attribute__((ext_vector_type(4))) float f32x4;

__device__ __forceinline__ unsigned bf16_rne(float f) {
  unsigned u = __float_as_uint(f);
  return (u + 0x7fff + ((u >> 16) & 1)) >> 16;
}

__device__ __forceinline__ float lrelu_exp(float v) {
  v = v > 0.f ? v : NEG_SLOPE * v;
  return __expf(v);  // no max-subtraction: |v| <~ 10, fp32-safe; normalized
                     // by the denominator so it matches the reference softmax
}

// In-block recompute of the block-level scan: blk_sums has nb (<=64)
// entries; first wave scans them into s_blk_off.
__device__ __forceinline__ void local_blk_scan(const int* __restrict__ blk_sums,
                                               int* s_blk_off, int nb, int t) {
  if (t < 64) {
    const int v = (t < nb) ? blk_sums[t] : 0;
    int incl = v;
#pragma unroll
    for (int d = 1; d < 64; d <<= 1) {
      const int o = __shfl_up(incl, d);
      if (t >= d) incl += o;
    }
    s_blk_off[t] = incl - v;
  }
}

// ---------------------------------------------------------------------------
// Fused kernel 1, 512 threads (R17-proven): blocks [0,G) = MFMA GEMM over 128
// node-rows (8 waves, wave w = rows w*16..+15); blocks [G,G+PB) = bucket
// histogram (stride-512 loop). GEMM: 8 col-tiles of 16, K=128 as 4
// MFMA(16x16x32). A/B share the same (g=lane>>4, j)->k convention so any hw
// k-permutation cancels. C/D: col=lane&15, row=(lane>>4)*4+reg.
// ---------------------------------------------------------------------------
__global__ __launch_bounds__(512) void gemm_hist(
    const float* __restrict__ x, const float* __restrict__ fc_w,
    const float* __restrict__ attn_l, const float* __restrict__ attn_r,
    const int* __restrict__ dst, unsigned* __restrict__ featb,
    float* __restrict__ el, float* __restrict__ er, int* __restrict__ hist,
    int N, int E, int NB, int chunk, int G)
{
  __shared__ __align__(16) unsigned w_lds[128 * 68];
  __shared__ int h[512];
  const int t = threadIdx.x;

  if (blockIdx.x >= G) {
    // ---- histogram part ----
    const int k = blockIdx.x - G;
    for (int i = t; i < NB; i += 512) h[i] = 0;
    __syncthreads();
    const int beg = k * chunk, end = min(E, beg + chunk);
    for (int e = beg + t; e < end; e += 512)
      atomicAdd(&h[dst[e] >> BKT_SHIFT], 1);
    __syncthreads();
    for (int i = t; i < NB; i += 512) hist[i * PB + k] = h[i];
    return;
  }

  // ---- gemm part ----
  const int row_base = blockIdx.x * 128;
  // stage fc_w fp32 -> bf16 pair words in LDS: 2048 uint4 slots, 4/thread.
  {
#pragma unroll
    for (int k = 0; k < 4; ++k) {
      const int i4 = t + k * 512;
      const int row = i4 >> 4;
      const int w0 = (i4 & 15) * 4;  // first of 4 words = 8 fp32
      const float4 v0 =
          *reinterpret_cast<const float4*>(fc_w + (size_t)row * 128 + w0 * 2);
      const float4 v1 = *reinterpret_cast<const float4*>(
          fc_w + (size_t)row * 128 + w0 * 2 + 4);
      unsigned* d = &w_lds[row * 68 + w0];
      d[0] = bf16_rne(v0.x) | (bf16_rne(v0.y) << 16);
      d[1] = bf16_rne(v0.z) | (bf16_rne(v0.w) << 16);
      d[2] = bf16_rne(v1.x) | (bf16_rne(v1.y) << 16);
      d[3] = bf16_rne(v1.z) | (bf16_rne(v1.w) << 16);
    }
  }

  const int w = t >> 6;         // wave id 0..7
  const int l = t & 63;
  const int cl = l & 15;        // free index (A row / B col / D col)
  const int g = l >> 4;         // k-group

  const int arow = min(row_base + w * 16 + cl, N - 1);
  const float* __restrict__ xp = x + (size_t)arow * 128;
  bf16x8 a_frag[4];
#pragma unroll
  for (int ks = 0; ks < 4; ++ks) {
    const float4 v0 = *reinterpret_cast<const float4*>(xp + ks * 32 + g * 8);
    const float4 v1 =
        *reinterpret_cast<const float4*>(xp + ks * 32 + g * 8 + 4);
    uint4 uu;
    uu.x = bf16_rne(v0.x) | (bf16_rne(v0.y) << 16);
    uu.y = bf16_rne(v0.z) | (bf16_rne(v0.w) << 16);
    uu.z = bf16_rne(v1.x) | (bf16_rne(v1.y) << 16);
    uu.w = bf16_rne(v1.z) | (bf16_rne(v1.w) << 16);
    a_frag[ks] = *reinterpret_cast<bf16x8*>(&uu);
  }
  __syncthreads();

  f32x4 acc[8];
#pragma unroll
  for (int ct = 0; ct < 8; ++ct) acc[ct] = (f32x4){0.f, 0.f, 0.f, 0.f};

#pragma unroll
  for (int ct = 0; ct < 8; ++ct) {
#pragma unroll
    for (int ks = 0; ks < 4; ++ks) {
      const bf16x8 b_frag = *reinterpret_cast<const bf16x8*>(
          &w_lds[(ct * 16 + cl) * 68 + ks * 16 + g * 4]);
      acc[ct] = __builtin_amdgcn_mfma_f32_16x16x32_bf16(a_frag[ks], b_frag,
                                                        acc[ct], 0, 0, 0);
    }
  }

#pragma unroll
  for (int ct = 0; ct < 8; ++ct) {
#pragma unroll
    for (int r = 0; r < 4; ++r) {
      const float v = acc[ct][r];
      const float vn = __shfl_xor(v, 1);
      const int node = row_base + w * 16 + g * 4 + r;
      if ((cl & 1) == 0 && node < N) {
        featb[(size_t)node * 64 + ct * 8 + (cl >> 1)] =
            bf16_rne(v) | (bf16_rne(vn) << 16);
      }
    }
  }

  float al_lo[4], al_hi[4], ar_lo[4], ar_hi[4];
#pragma unroll
  for (int hh = 0; hh < 4; ++hh) {
    al_lo[hh] = attn_l[hh * 32 + cl];
    al_hi[hh] = attn_l[hh * 32 + 16 + cl];
    ar_lo[hh] = attn_r[hh * 32 + cl];
    ar_hi[hh] = attn_r[hh * 32 + 16 + cl];
  }
#pragma unroll
  for (int r = 0; r < 4; ++r) {
    const int node = row_base + w * 16 + g * 4 + r;
#pragma unroll
    for (int hh = 0; hh < 4; ++hh) {
      float pl = acc[2 * hh][r] * al_lo[hh] + acc[2 * hh + 1][r] * al_hi[hh];
      float pr = acc[2 * hh][r] * ar_lo[hh] + acc[2 * hh + 1][r] * ar_hi[hh];
#pragma unroll
      for (int d = 1; d < 16; d <<= 1) {
        pl += __shfl_xor(pl, d);
        pr += __shfl_xor(pr, d);
      }
      if (cl == 0 && node < N) {
        el[(size_t)node * 4 + hh] = pl;
        er[(size_t)node * 4 + hh] = pr;
      }
    }
  }
}

// Scan of the hist matrix in 8192-entry chunks (32/thread, two-pass:
// sum, then re-read + write running prefix; re-read is L2-hot). nb <= 64.
__global__ __launch_bounds__(256) void scan_a(const int* __restrict__ hist,
                                              int* __restrict__ hscan,
                                              int* __restrict__ blk_sums,
                                              int n) {
  __shared__ int wsum[4];
  const int b = blockIdx.x, t = threadIdx.x;
  const int base = b * SCHUNK + t * 32;
  int s = 0;
#pragma unroll
  for (int j = 0; j < 32; ++j) s += (base + j < n) ? hist[base + j] : 0;
  const int lane = t & 63;
  int incl = s;
#pragma unroll
  for (int d = 1; d < 64; d <<= 1) {
    const int o = __shfl_up(incl, d);
    if (lane >= d) incl += o;
  }
  const int w = t >> 6;
  if (lane == 63) wsum[w] = incl;
  __syncthreads();
  int woff = 0;
  for (int ww = 0; ww < w; ++ww) woff += wsum[ww];
  int run = woff + incl - s;
#pragma unroll
  for (int j = 0; j < 32; ++j) {
    if (base + j < n) {
      hscan[base + j] = run;
      run += hist[base + j];
    }
  }
  if (t == 255) blk_sums[b] = woff + incl;
}

// Partition edges into bucket-contiguous regions; per-(bucket,block) region is
// exclusive to this block. Edge packed in 4B: src(20b) | local_dst(8b)<<20.
// hscan is chunk-local; global base = s_blk_off[idx>>SSHIFT]. PB=1024 blocks
// x 512 thr: ~1563 edges/block (4 blocks/CU latency hiding).
__global__ __launch_bounds__(512) void part_scatter(
    const int* __restrict__ src, const int* __restrict__ dst,
    const int* __restrict__ hscan, const int* __restrict__ blk_sums,
    unsigned* __restrict__ part, int E, int NB, int chunk, int nb) {
  __shared__ int cur[512];
  __shared__ int s_blk_off[64];
  const int k = blockIdx.x, t = threadIdx.x;
  local_blk_scan(blk_sums, s_blk_off, nb, t);
  __syncthreads();
  for (int i = t; i < NB; i += 512) {
    const int m = i * PB + k;
    cur[i] = hscan[m] + s_blk_off[m >> SSHIFT];
  }
  __syncthreads();
  const int beg = k * chunk, end = min(E, beg + chunk);
  for (int e = beg + t; e < end; e += 512) {
    const int d = dst[e];
    const int b = d >> BKT_SHIFT;
    const int pos = atomicAdd(&cur[b], 1);
    part[pos] = (unsigned)src[e] |
                ((unsigned)(d & ((1 << BKT_SHIFT) - 1)) << 20);
  }
}

// One block (512 thr, 8 waves) per bucket. Phases: (1) LDS count, (2) scan
// (first 4 waves), (3) cursor scatter of the packed word into CSR order
// (pure permutation), (4) sequential re-read of the just-written csr range
// (same-XCD L2-hot) computing w[h] = exp(lrelu(el[s][h]+er[d][h])) as
// 4 x bf16, written COALESCED.
__global__ __launch_bounds__(512) void build_csr(
    const unsigned* __restrict__ part, const int* __restrict__ hscan,
    const int* __restrict__ blk_sums, const float* __restrict__ el,
    const float* __restrict__ er, int* __restrict__ node_offs,
    unsigned* __restrict__ csr, uint2* __restrict__ wsb,
    int N, int E, int NB, int nb) {
  __shared__ int cnt[256];
  __shared__ int wtot[4];
  __shared__ int s_blk_off[64];
  const int b = blockIdx.x, t = threadIdx.x;
  local_blk_scan(blk_sums, s_blk_off, nb, t);
  if (t < 256) cnt[t] = 0;
  __syncthreads();
  const int m0 = b * PB;
  const int bbase = hscan[m0] + s_blk_off[m0 >> SSHIFT];
  int bend = E;
  if (b + 1 < NB) {
    const int m1 = (b + 1) * PB;
    bend = hscan[m1] + s_blk_off[m1 >> SSHIFT];
  }
  const int node0 = b << BKT_SHIFT;
  for (int p = bbase + t; p < bend; p += 512)
    atomicAdd(&cnt[part[p] >> 20], 1);
  __syncthreads();
  int a0 = 0, incl = 0;
  if (t < 256) {  // waves 0..3 only (whole waves, no intra-wave divergence)
    a0 = cnt[t];
    incl = a0;
#pragma unroll
    for (int d1 = 1; d1 < 64; d1 <<= 1) {
      const int o = __shfl_up(incl, d1);
      if ((t & 63) >= d1) incl += o;
    }
    if ((t & 63) == 63) wtot[t >> 6] = incl;
  }
  __syncthreads();
  if (t < 256) {
    const int w = t >> 6;
    int woff = 0;
    for (int ww = 0; ww < w; ++ww) woff += wtot[ww];
    const int e0 = woff + incl - a0;  // exclusive offset of node t
    cnt[t] = e0;                      // reuse as cursor
    if (node0 + t < N) node_offs[node0 + t] = bbase + e0;
    if (b == NB - 1 && t == 0) node_offs[N] = E;
  }
  __syncthreads();
  for (int p = bbase + t; p < bend; p += 512) {
    const unsigned v = part[p];
    const int lpos = atomicAdd(&cnt[v >> 20], 1);
    csr[bbase + lpos] = v;
  }
  __syncthreads();
  // phase 4: coalesced w computation over the finished CSR range
  for (int p = bbase + t; p < bend; p += 512) {
    const unsigned v = csr[p];
    const unsigned s = v & 0xFFFFFu;
    const unsigned ld = v >> 20;
    const float4 l4 = *reinterpret_cast<const float4*>(el + s * 4);
    const float4 r4 =
        *reinterpret_cast<const float4*>(er + (unsigned)(node0 + ld) * 4);
    uint2 u;
    u.x = bf16_rne(lrelu_exp(l4.x + r4.x)) |
          (bf16_rne(lrelu_exp(l4.y + r4.y)) << 16);
    u.y = bf16_rne(lrelu_exp(l4.z + r4.z)) |
          (bf16_rne(lrelu_exp(l4.w + r4.w)) << 16);
    wsb[p] = u;
  }
}

// ---------------------------------------------------------------------------
// Pull aggregation (R13/R17-proven): quarter-wave, 16-edge groups (4 chains
// in flight per lane). Wave per node; lane l = (q=l>>4, li=l&15). Lane li
// owns elems {8li..8li+7} (one uint4 of featb; head hh=li>>2); quarter q
// processes edges p+4i+q. Quarters combined via shfl_xor(16)+(32).
// ---------------------------------------------------------------------------
__global__ __launch_bounds__(256) void agg_kernel(
    const uint4* __restrict__ featb4, const unsigned* __restrict__ csr,
    const unsigned short* __restrict__ wsb_us, const float* __restrict__ x,
    const float* __restrict__ bias, const int* __restrict__ node_offs,
    float* __restrict__ out, int N, int E)
{
  const int n = (int)((blockIdx.x * (size_t)blockDim.x + threadIdx.x) >> 6);
  if (n >= N) return;
  const unsigned lane = threadIdx.x & 63;
  const unsigned q = lane >> 4;
  const unsigned li = lane & 15;
  const unsigned hh = li >> 2;        // head of this lane's 8 elems
  const unsigned short* __restrict__ wp = wsb_us + hh;  // per-lane head base
  const int beg = node_offs[n];
  const int end = node_offs[n + 1];
  const int nfull = (end - beg) >> 4;

  float a0 = 0.f, a1 = 0.f, a2 = 0.f, a3 = 0.f;
  float a4 = 0.f, a5 = 0.f, a6 = 0.f, a7 = 0.f, ds = 0.f;
  int p = beg;
  for (int gi = 0; gi < nfull; ++gi, p += 16) {
    unsigned pk[4]; unsigned wu[4]; uint4 fv[4];
#pragma unroll
    for (int i = 0; i < 4; ++i) pk[i] = csr[(unsigned)p + 4 * i + q];
#pragma unroll
    for (int i = 0; i < 4; ++i)
      wu[i] = wp[((unsigned)p + 4 * i + q) * 4];
#pragma unroll
    for (int i = 0; i < 4; ++i)
      fv[i] = featb4[(pk[i] & 0xFFFFFu) * 16 + li];
#pragma unroll
    for (int i = 0; i < 4; ++i) {
      const float w = __uint_as_float(wu[i] << 16);
      a0 = fmaf(w, __uint_as_float(fv[i].x << 16), a0);
      a1 = fmaf(w, __uint_as_float(fv[i].x & 0xffff0000u), a1);
      a2 = fmaf(w, __uint_as_float(fv[i].y << 16), a2);
      a3 = fmaf(w, __uint_as_float(fv[i].y & 0xffff0000u), a3);
      a4 = fmaf(w, __uint_as_float(fv[i].z << 16), a4);
      a5 = fmaf(w, __uint_as_float(fv[i].z & 0xffff0000u), a5);
      a6 = fmaf(w, __uint_as_float(fv[i].w << 16), a6);
      a7 = fmaf(w, __uint_as_float(fv[i].w & 0xffff0000u), a7);
      ds += w;
    }
  }
  if (p < end) {  // predicated tail group (<16 edges)
    const int last = end - 1;
    unsigned pk[4]; unsigned wu[4]; uint4 fv[4]; int ee[4];
#pragma unroll
    for (int i = 0; i < 4; ++i) ee[i] = p + 4 * i + (int)q;
#pragma unroll
    for (int i = 0; i < 4; ++i) pk[i] = csr[(unsigned)min(ee[i], last)];
#pragma unroll
    for (int i = 0; i < 4; ++i)
      wu[i] = wp[(unsigned)min(ee[i], last) * 4];
#pragma unroll
    for (int i = 0; i < 4; ++i)
      fv[i] = featb4[(pk[i] & 0xFFFFFu) * 16 + li];
#pragma unroll
    for (int i = 0; i < 4; ++i) {
      float w = __uint_as_float(wu[i] << 16);
      if (ee[i] > last) w = 0.f;
      a0 = fmaf(w, __uint_as_float(fv[i].x << 16), a0);
      a1 = fmaf(w, __uint_as_float(fv[i].x & 0xffff0000u), a1);
      a2 = fmaf(w, __uint_as_float(fv[i].y << 16), a2);
      a3 = fmaf(w, __uint_as_float(fv[i].y & 0xffff0000u), a3);
      a4 = fmaf(w, __uint_as_float(fv[i].z << 16), a4);
      a5 = fmaf(w, __uint_as_float(fv[i].z & 0xffff0000u), a5);
      a6 = fmaf(w, __uint_as_float(fv[i].w << 16), a6);
      a7 = fmaf(w, __uint_as_float(fv[i].w & 0xffff0000u), a7);
      ds += w;
    }
  }

  a0 += __shfl_xor(a0, 16); a0 += __shfl_xor(a0, 32);
  a1 += __shfl_xor(a1, 16); a1 += __shfl_xor(a1, 32);
  a2 += __shfl_xor(a2, 16); a2 += __shfl_xor(a2, 32);
  a3 += __shfl_xor(a3, 16); a3 += __shfl_xor(a3, 32);
  a4 += __shfl_xor(a4, 16); a4 += __shfl_xor(a4, 32);
  a5 += __shfl_xor(a5, 16); a5 += __shfl_xor(a5, 32);
  a6 += __shfl_xor(a6, 16); a6 += __shfl_xor(a6, 32);
  a7 += __shfl_xor(a7, 16); a7 += __shfl_xor(a7, 32);
  ds += __shfl_xor(ds, 16); ds += __shfl_xor(ds, 32);

  if (q == 0) {
    const float inv = 1.f / fmaxf(ds, 1e-38f);
    const float4 x0 = ((const float4*)x)[(unsigned)n * 32 + 2 * li];
    const float4 x1 = ((const float4*)x)[(unsigned)n * 32 + 2 * li + 1];
    const float4 b0 = ((const float4*)bias)[2 * li];
    const float4 b1 = ((const float4*)bias)[2 * li + 1];
    float4 o0, o1;
    o0.x = fmaf(a0, inv, x0.x + b0.x);
    o0.y = fmaf(a1, inv, x0.y + b0.y);
    o0.z = fmaf(a2, inv, x0.z + b0.z);
    o0.w = fmaf(a3, inv, x0.w + b0.w);
    o1.x = fmaf(a4, inv, x1.x + b1.x);
    o1.y = fmaf(a5, inv, x1.y + b1.y);
    o1.z = fmaf(a6, inv, x1.z + b1.z);
    o1.w = fmaf(a7, inv, x1.w + b1.w);
    ((float4*)out)[(unsigned)n * 32 + 2 * li] = o0;
    ((float4*)out)[(unsigned)n * 32 + 2 * li + 1] = o1;
  }
}

// ---------------------------------------------------------------------------
extern "C" void kernel_launch(void* const* d_in, const int* in_sizes, int n_in,
                              void* d_out, int out_size, void* d_ws,
                              size_t ws_size, hipStream_t stream) {
  const float* x      = (const float*)d_in[0];
  const float* fc_w   = (const float*)d_in[1];
  const float* attn_l = (const float*)d_in[2];
  const float* attn_r = (const float*)d_in[3];
  const float* bias   = (const float*)d_in[4];
  const int*   src    = (const int*)d_in[5];
  const int*   dst    = (const int*)d_in[6];
  const int N = in_sizes[0] / 128;
  const int E = in_sizes[5];
  float* out = (float*)d_out;

  const int NB = (N + 255) >> 8;        // 391 buckets (NB <= 512 assumed)
  const int M = NB * PB;                // hist entries (~400K)
  const int chunk = (E + PB - 1) / PB;  // edges per partition block (~1563)
  const int nb = (M + SCHUNK - 1) / SCHUNK;  // 49 scan blocks (must be <= 64)

  char* ws = (char*)d_ws;
  size_t off = 0;
  auto alloc = [&](size_t bytes) {
    void* p = ws + off;
    off += (bytes + 255) & ~(size_t)255;
    return p;
  };
  unsigned* featb   = (unsigned*)alloc((size_t)N * 128 * 2);
  float* el         = (float*)alloc((size_t)N * 4 * 4);
  float* er         = (float*)alloc((size_t)N * 4 * 4);
  int*   hist       = (int*)alloc((size_t)M * 4);
  int*   hscan      = (int*)alloc((size_t)(M + 1) * 4);
  int*   node_offs  = (int*)alloc((size_t)(N + 1) * 4);
  int*   blk_sums   = (int*)alloc(256);
  unsigned* part    = (unsigned*)alloc((size_t)E * 4);
  unsigned* csr     = (unsigned*)alloc((size_t)E * 4);
  uint2* wsb        = (uint2*)alloc((size_t)E * 8);

  const int G = (N + 127) / 128;  // 782 gemm blocks (128 rows each)
  gemm_hist<<<G + PB, 512, 0, stream>>>(x, fc_w, attn_l, attn_r, dst, featb,
                                        el, er, hist, N, E, NB, chunk, G);
  scan_a<<<nb, 256, 0, stream>>>(hist, hscan, blk_sums, M);
  part_scatter<<<PB, 512, 0, stream>>>(src, dst, hscan, blk_sums, part, E,
                                       NB, chunk, nb);
  build_csr<<<NB, 512, 0, stream>>>(part, hscan, blk_sums, el, er, node_offs,
                                    csr, wsb, N, E, NB, nb);
  agg_kernel<<<(N + 3) / 4, 256, 0, stream>>>((const uint4*)featb, csr,
                                              (const unsigned short*)wsb, x,
                                              bias, node_offs, out, N, E);
}

// Round 21
// 142.602 us; speedup vs baseline: 1.0993x; 1.0993x over previous
//
#include <hip/hip_runtime.h>
#include <math.h>

#define NEG_SLOPE 0.2f
#define PB 512        // partition blocks (fixed chunking shared by hist/scatter)
#define BKT_SHIFT 8   // 256 nodes per bucket (R15-proven)
#define SCHUNK 4096   // hist entries per scan_a block
#define SSHIFT 12

typedef __attribute__((ext_vector_type(8))) short bf16x8;
typedef __attribute__((ext_vector_type(4))) float f32x4;

__device__ __forceinline__ unsigned bf16_rne(float f) {
  unsigned u = __float_as_uint(f);
  return (u + 0x7fff + ((u >> 16) & 1)) >> 16;
}

__device__ __forceinline__ float lrelu_exp(float v) {
  v = v > 0.f ? v : NEG_SLOPE * v;
  return __expf(v);  // no max-subtraction: |v| <~ 10, fp32-safe; normalized
                     // by the denominator so it matches the reference softmax
}

// In-block recompute of the block-level scan: blk_sums has nb (<=64)
// entries; first wave scans them into s_blk_off.
__device__ __forceinline__ void local_blk_scan(const int* __restrict__ blk_sums,
                                               int* s_blk_off, int nb, int t) {
  if (t < 64) {
    const int v = (t < nb) ? blk_sums[t] : 0;
    int incl = v;
#pragma unroll
    for (int d = 1; d < 64; d <<= 1) {
      const int o = __shfl_up(incl, d);
      if (t >= d) incl += o;
    }
    s_blk_off[t] = incl - v;
  }
}

// ---------------------------------------------------------------------------
// Fused kernel 1, 512 threads (R17-proven): blocks [0,G) = MFMA GEMM over 128
// node-rows (8 waves, wave w = rows w*16..+15); blocks [G,G+PB) = bucket
// histogram (stride-512 loop). GEMM: 8 col-tiles of 16, K=128 as 4
// MFMA(16x16x32). A/B share the same (g=lane>>4, j)->k convention so any hw
// k-permutation cancels. C/D: col=lane&15, row=(lane>>4)*4+reg.
// ---------------------------------------------------------------------------
__global__ __launch_bounds__(512) void gemm_hist(
    const float* __restrict__ x, const float* __restrict__ fc_w,
    const float* __restrict__ attn_l, const float* __restrict__ attn_r,
    const int* __restrict__ dst, unsigned* __restrict__ featb,
    float* __restrict__ el, float* __restrict__ er, int* __restrict__ hist,
    int N, int E, int NB, int chunk, int G)
{
  __shared__ __align__(16) unsigned w_lds[128 * 68];
  __shared__ int h[512];
  const int t = threadIdx.x;

  if (blockIdx.x >= G) {
    // ---- histogram part ----
    const int k = blockIdx.x - G;
    for (int i = t; i < NB; i += 512) h[i] = 0;
    __syncthreads();
    const int beg = k * chunk, end = min(E, beg + chunk);
    for (int e = beg + t; e < end; e += 512)
      atomicAdd(&h[dst[e] >> BKT_SHIFT], 1);
    __syncthreads();
    for (int i = t; i < NB; i += 512) hist[i * PB + k] = h[i];
    return;
  }

  // ---- gemm part ----
  const int row_base = blockIdx.x * 128;
  // stage fc_w fp32 -> bf16 pair words in LDS: 2048 uint4 slots, 4/thread.
  {
#pragma unroll
    for (int k = 0; k < 4; ++k) {
      const int i4 = t + k * 512;
      const int row = i4 >> 4;
      const int w0 = (i4 & 15) * 4;  // first of 4 words = 8 fp32
      const float4 v0 =
          *reinterpret_cast<const float4*>(fc_w + (size_t)row * 128 + w0 * 2);
      const float4 v1 = *reinterpret_cast<const float4*>(
          fc_w + (size_t)row * 128 + w0 * 2 + 4);
      unsigned* d = &w_lds[row * 68 + w0];
      d[0] = bf16_rne(v0.x) | (bf16_rne(v0.y) << 16);
      d[1] = bf16_rne(v0.z) | (bf16_rne(v0.w) << 16);
      d[2] = bf16_rne(v1.x) | (bf16_rne(v1.y) << 16);
      d[3] = bf16_rne(v1.z) | (bf16_rne(v1.w) << 16);
    }
  }

  const int w = t >> 6;         // wave id 0..7
  const int l = t & 63;
  const int cl = l & 15;        // free index (A row / B col / D col)
  const int g = l >> 4;         // k-group

  const int arow = min(row_base + w * 16 + cl, N - 1);
  const float* __restrict__ xp = x + (size_t)arow * 128;
  bf16x8 a_frag[4];
#pragma unroll
  for (int ks = 0; ks < 4; ++ks) {
    const float4 v0 = *reinterpret_cast<const float4*>(xp + ks * 32 + g * 8);
    const float4 v1 =
        *reinterpret_cast<const float4*>(xp + ks * 32 + g * 8 + 4);
    uint4 uu;
    uu.x = bf16_rne(v0.x) | (bf16_rne(v0.y) << 16);
    uu.y = bf16_rne(v0.z) | (bf16_rne(v0.w) << 16);
    uu.z = bf16_rne(v1.x) | (bf16_rne(v1.y) << 16);
    uu.w = bf16_rne(v1.z) | (bf16_rne(v1.w) << 16);
    a_frag[ks] = *reinterpret_cast<bf16x8*>(&uu);
  }
  __syncthreads();

  f32x4 acc[8];
#pragma unroll
  for (int ct = 0; ct < 8; ++ct) acc[ct] = (f32x4){0.f, 0.f, 0.f, 0.f};

#pragma unroll
  for (int ct = 0; ct < 8; ++ct) {
#pragma unroll
    for (int ks = 0; ks < 4; ++ks) {
      const bf16x8 b_frag = *reinterpret_cast<const bf16x8*>(
          &w_lds[(ct * 16 + cl) * 68 + ks * 16 + g * 4]);
      acc[ct] = __builtin_amdgcn_mfma_f32_16x16x32_bf16(a_frag[ks], b_frag,
                                                        acc[ct], 0, 0, 0);
    }
  }

#pragma unroll
  for (int ct = 0; ct < 8; ++ct) {
#pragma unroll
    for (int r = 0; r < 4; ++r) {
      const float v = acc[ct][r];
      const float vn = __shfl_xor(v, 1);
      const int node = row_base + w * 16 + g * 4 + r;
      if ((cl & 1) == 0 && node < N) {
        featb[(size_t)node * 64 + ct * 8 + (cl >> 1)] =
            bf16_rne(v) | (bf16_rne(vn) << 16);
      }
    }
  }

  float al_lo[4], al_hi[4], ar_lo[4], ar_hi[4];
#pragma unroll
  for (int hh = 0; hh < 4; ++hh) {
    al_lo[hh] = attn_l[hh * 32 + cl];
    al_hi[hh] = attn_l[hh * 32 + 16 + cl];
    ar_lo[hh] = attn_r[hh * 32 + cl];
    ar_hi[hh] = attn_r[hh * 32 + 16 + cl];
  }
#pragma unroll
  for (int r = 0; r < 4; ++r) {
    const int node = row_base + w * 16 + g * 4 + r;
#pragma unroll
    for (int hh = 0; hh < 4; ++hh) {
      float pl = acc[2 * hh][r] * al_lo[hh] + acc[2 * hh + 1][r] * al_hi[hh];
      float pr = acc[2 * hh][r] * ar_lo[hh] + acc[2 * hh + 1][r] * ar_hi[hh];
#pragma unroll
      for (int d = 1; d < 16; d <<= 1) {
        pl += __shfl_xor(pl, d);
        pr += __shfl_xor(pr, d);
      }
      if (cl == 0 && node < N) {
        el[(size_t)node * 4 + hh] = pl;
        er[(size_t)node * 4 + hh] = pr;
      }
    }
  }
}

// Scan of the hist matrix in 4096-entry chunks (16/thread) -> nb stays <= 64.
__global__ __launch_bounds__(256) void scan_a(const int* __restrict__ deg,
                                              int* __restrict__ offs,
                                              int* __restrict__ blk_sums,
                                              int n) {
  __shared__ int wsum[4];
  const int b = blockIdx.x, t = threadIdx.x;
  const int base = b * SCHUNK + t * 16;
  int v[16];
  int s = 0;
#pragma unroll
  for (int j = 0; j < 16; ++j) {
    v[j] = s;
    const int d = (base + j < n) ? deg[base + j] : 0;
    s += d;
  }
  const int lane = t & 63;
  int incl = s;
#pragma unroll
  for (int d = 1; d < 64; d <<= 1) {
    const int o = __shfl_up(incl, d);
    if (lane >= d) incl += o;
  }
  const int w = t >> 6;
  if (lane == 63) wsum[w] = incl;
  __syncthreads();
  int woff = 0;
  for (int ww = 0; ww < w; ++ww) woff += wsum[ww];
  const int thr_excl = woff + incl - s;
#pragma unroll
  for (int j = 0; j < 16; ++j)
    if (base + j < n) offs[base + j] = thr_excl + v[j];
  if (t == 255) blk_sums[b] = woff + incl;
}

// Partition edges into bucket-contiguous regions; per-(bucket,block) region is
// exclusive to this block. Edge packed in 4B: src(20b) | local_dst(8b)<<20.
// hscan is chunk-local; global base = s_blk_off[idx>>SSHIFT]. PB=512 blocks
// x 512 thr: ~3125 edges/block (2 blocks/CU latency hiding).
__global__ __launch_bounds__(512) void part_scatter(
    const int* __restrict__ src, const int* __restrict__ dst,
    const int* __restrict__ hscan, const int* __restrict__ blk_sums,
    unsigned* __restrict__ part, int E, int NB, int chunk, int nb) {
  __shared__ int cur[512];
  __shared__ int s_blk_off[64];
  const int k = blockIdx.x, t = threadIdx.x;
  local_blk_scan(blk_sums, s_blk_off, nb, t);
  __syncthreads();
  for (int i = t; i < NB; i += 512) {
    const int m = i * PB + k;
    cur[i] = hscan[m] + s_blk_off[m >> SSHIFT];
  }
  __syncthreads();
  const int beg = k * chunk, end = min(E, beg + chunk);
  for (int e = beg + t; e < end; e += 512) {
    const int d = dst[e];
    const int b = d >> BKT_SHIFT;
    const int pos = atomicAdd(&cur[b], 1);
    part[pos] = (unsigned)src[e] |
                ((unsigned)(d & ((1 << BKT_SHIFT) - 1)) << 20);
  }
}

// One block (512 thr, 8 waves) per bucket. Phases: (1) LDS count, (2) scan
// (first 4 waves), (3) cursor scatter of the packed word into CSR order
// (pure permutation), (4) sequential re-read of the just-written csr range
// (same-XCD L2-hot) computing w[h] = exp(lrelu(el[s][h]+er[d][h])) as
// 4 x bf16, written COALESCED.
__global__ __launch_bounds__(512) void build_csr(
    const unsigned* __restrict__ part, const int* __restrict__ hscan,
    const int* __restrict__ blk_sums, const float* __restrict__ el,
    const float* __restrict__ er, int* __restrict__ node_offs,
    unsigned* __restrict__ csr, uint2* __restrict__ wsb,
    int N, int E, int NB, int nb) {
  __shared__ int cnt[256];
  __shared__ int wtot[4];
  __shared__ int s_blk_off[64];
  const int b = blockIdx.x, t = threadIdx.x;
  local_blk_scan(blk_sums, s_blk_off, nb, t);
  if (t < 256) cnt[t] = 0;
  __syncthreads();
  const int m0 = b * PB;
  const int bbase = hscan[m0] + s_blk_off[m0 >> SSHIFT];
  int bend = E;
  if (b + 1 < NB) {
    const int m1 = (b + 1) * PB;
    bend = hscan[m1] + s_blk_off[m1 >> SSHIFT];
  }
  const int node0 = b << BKT_SHIFT;
  for (int p = bbase + t; p < bend; p += 512)
    atomicAdd(&cnt[part[p] >> 20], 1);
  __syncthreads();
  int a0 = 0, incl = 0;
  if (t < 256) {  // waves 0..3 only (whole waves, no intra-wave divergence)
    a0 = cnt[t];
    incl = a0;
#pragma unroll
    for (int d1 = 1; d1 < 64; d1 <<= 1) {
      const int o = __shfl_up(incl, d1);
      if ((t & 63) >= d1) incl += o;
    }
    if ((t & 63) == 63) wtot[t >> 6] = incl;
  }
  __syncthreads();
  if (t < 256) {
    const int w = t >> 6;
    int woff = 0;
    for (int ww = 0; ww < w; ++ww) woff += wtot[ww];
    const int e0 = woff + incl - a0;  // exclusive offset of node t
    cnt[t] = e0;                      // reuse as cursor
    if (node0 + t < N) node_offs[node0 + t] = bbase + e0;
    if (b == NB - 1 && t == 0) node_offs[N] = E;
  }
  __syncthreads();
  for (int p = bbase + t; p < bend; p += 512) {
    const unsigned v = part[p];
    const int lpos = atomicAdd(&cnt[v >> 20], 1);
    csr[bbase + lpos] = v;
  }
  __syncthreads();
  // phase 4: coalesced w computation over the finished CSR range
  for (int p = bbase + t; p < bend; p += 512) {
    const unsigned v = csr[p];
    const unsigned s = v & 0xFFFFFu;
    const unsigned ld = v >> 20;
    const float4 l4 = *reinterpret_cast<const float4*>(el + s * 4);
    const float4 r4 =
        *reinterpret_cast<const float4*>(er + (unsigned)(node0 + ld) * 4);
    uint2 u;
    u.x = bf16_rne(lrelu_exp(l4.x + r4.x)) |
          (bf16_rne(lrelu_exp(l4.y + r4.y)) << 16);
    u.y = bf16_rne(lrelu_exp(l4.z + r4.z)) |
          (bf16_rne(lrelu_exp(l4.w + r4.w)) << 16);
    wsb[p] = u;
  }
}

// ---------------------------------------------------------------------------
// Pull aggregation (R13/R17-proven): quarter-wave, 16-edge groups (4 chains
// in flight per lane). Wave per node; lane l = (q=l>>4, li=l&15). Lane li
// owns elems {8li..8li+7} (one uint4 of featb; head hh=li>>2); quarter q
// processes edges p+4i+q. Quarters combined via shfl_xor(16)+(32).
// ---------------------------------------------------------------------------
__global__ __launch_bounds__(256) void agg_kernel(
    const uint4* __restrict__ featb4, const unsigned* __restrict__ csr,
    const unsigned short* __restrict__ wsb_us, const float* __restrict__ x,
    const float* __restrict__ bias, const int* __restrict__ node_offs,
    float* __restrict__ out, int N, int E)
{
  const int n = (int)((blockIdx.x * (size_t)blockDim.x + threadIdx.x) >> 6);
  if (n >= N) return;
  const unsigned lane = threadIdx.x & 63;
  const unsigned q = lane >> 4;
  const unsigned li = lane & 15;
  const unsigned hh = li >> 2;        // head of this lane's 8 elems
  const unsigned short* __restrict__ wp = wsb_us + hh;  // per-lane head base
  const int beg = node_offs[n];
  const int end = node_offs[n + 1];
  const int nfull = (end - beg) >> 4;

  float a0 = 0.f, a1 = 0.f, a2 = 0.f, a3 = 0.f;
  float a4 = 0.f, a5 = 0.f, a6 = 0.f, a7 = 0.f, ds = 0.f;
  int p = beg;
  for (int gi = 0; gi < nfull; ++gi, p += 16) {
    unsigned pk[4]; unsigned wu[4]; uint4 fv[4];
#pragma unroll
    for (int i = 0; i < 4; ++i) pk[i] = csr[(unsigned)p + 4 * i + q];
#pragma unroll
    for (int i = 0; i < 4; ++i)
      wu[i] = wp[((unsigned)p + 4 * i + q) * 4];
#pragma unroll
    for (int i = 0; i < 4; ++i)
      fv[i] = featb4[(pk[i] & 0xFFFFFu) * 16 + li];
#pragma unroll
    for (int i = 0; i < 4; ++i) {
      const float w = __uint_as_float(wu[i] << 16);
      a0 = fmaf(w, __uint_as_float(fv[i].x << 16), a0);
      a1 = fmaf(w, __uint_as_float(fv[i].x & 0xffff0000u), a1);
      a2 = fmaf(w, __uint_as_float(fv[i].y << 16), a2);
      a3 = fmaf(w, __uint_as_float(fv[i].y & 0xffff0000u), a3);
      a4 = fmaf(w, __uint_as_float(fv[i].z << 16), a4);
      a5 = fmaf(w, __uint_as_float(fv[i].z & 0xffff0000u), a5);
      a6 = fmaf(w, __uint_as_float(fv[i].w << 16), a6);
      a7 = fmaf(w, __uint_as_float(fv[i].w & 0xffff0000u), a7);
      ds += w;
    }
  }
  if (p < end) {  // predicated tail group (<16 edges)
    const int last = end - 1;
    unsigned pk[4]; unsigned wu[4]; uint4 fv[4]; int ee[4];
#pragma unroll
    for (int i = 0; i < 4; ++i) ee[i] = p + 4 * i + (int)q;
#pragma unroll
    for (int i = 0; i < 4; ++i) pk[i] = csr[(unsigned)min(ee[i], last)];
#pragma unroll
    for (int i = 0; i < 4; ++i)
      wu[i] = wp[(unsigned)min(ee[i], last) * 4];
#pragma unroll
    for (int i = 0; i < 4; ++i)
      fv[i] = featb4[(pk[i] & 0xFFFFFu) * 16 + li];
#pragma unroll
    for (int i = 0; i < 4; ++i) {
      float w = __uint_as_float(wu[i] << 16);
      if (ee[i] > last) w = 0.f;
      a0 = fmaf(w, __uint_as_float(fv[i].x << 16), a0);
      a1 = fmaf(w, __uint_as_float(fv[i].x & 0xffff0000u), a1);
      a2 = fmaf(w, __uint_as_float(fv[i].y << 16), a2);
      a3 = fmaf(w, __uint_as_float(fv[i].y & 0xffff0000u), a3);
      a4 = fmaf(w, __uint_as_float(fv[i].z << 16), a4);
      a5 = fmaf(w, __uint_as_float(fv[i].z & 0xffff0000u), a5);
      a6 = fmaf(w, __uint_as_float(fv[i].w << 16), a6);
      a7 = fmaf(w, __uint_as_float(fv[i].w & 0xffff0000u), a7);
      ds += w;
    }
  }

  a0 += __shfl_xor(a0, 16); a0 += __shfl_xor(a0, 32);
  a1 += __shfl_xor(a1, 16); a1 += __shfl_xor(a1, 32);
  a2 += __shfl_xor(a2, 16); a2 += __shfl_xor(a2, 32);
  a3 += __shfl_xor(a3, 16); a3 += __shfl_xor(a3, 32);
  a4 += __shfl_xor(a4, 16); a4 += __shfl_xor(a4, 32);
  a5 += __shfl_xor(a5, 16); a5 += __shfl_xor(a5, 32);
  a6 += __shfl_xor(a6, 16); a6 += __shfl_xor(a6, 32);
  a7 += __shfl_xor(a7, 16); a7 += __shfl_xor(a7, 32);
  ds += __shfl_xor(ds, 16); ds += __shfl_xor(ds, 32);

  if (q == 0) {
    const float inv = 1.f / fmaxf(ds, 1e-38f);
    const float4 x0 = ((const float4*)x)[(unsigned)n * 32 + 2 * li];
    const float4 x1 = ((const float4*)x)[(unsigned)n * 32 + 2 * li + 1];
    const float4 b0 = ((const float4*)bias)[2 * li];
    const float4 b1 = ((const float4*)bias)[2 * li + 1];
    float4 o0, o1;
    o0.x = fmaf(a0, inv, x0.x + b0.x);
    o0.y = fmaf(a1, inv, x0.y + b0.y);
    o0.z = fmaf(a2, inv, x0.z + b0.z);
    o0.w = fmaf(a3, inv, x0.w + b0.w);
    o1.x = fmaf(a4, inv, x1.x + b1.x);
    o1.y = fmaf(a5, inv, x1.y + b1.y);
    o1.z = fmaf(a6, inv, x1.z + b1.z);
    o1.w = fmaf(a7, inv, x1.w + b1.w);
    ((float4*)out)[(unsigned)n * 32 + 2 * li] = o0;
    ((float4*)out)[(unsigned)n * 32 + 2 * li + 1] = o1;
  }
}

// ---------------------------------------------------------------------------
extern "C" void kernel_launch(void* const* d_in, const int* in_sizes, int n_in,
                              void* d_out, int out_size, void* d_ws,
                              size_t ws_size, hipStream_t stream) {
  const float* x      = (const float*)d_in[0];
  const float* fc_w   = (const float*)d_in[1];
  const float* attn_l = (const float*)d_in[2];
  const float* attn_r = (const float*)d_in[3];
  const float* bias   = (const float*)d_in[4];
  const int*   src    = (const int*)d_in[5];
  const int*   dst    = (const int*)d_in[6];
  const int N = in_sizes[0] / 128;
  const int E = in_sizes[5];
  float* out = (float*)d_out;

  const int NB = (N + 255) >> 8;        // 391 buckets (NB <= 512 assumed)
  const int M = NB * PB;                // hist entries (~200K)
  const int chunk = (E + PB - 1) / PB;  // edges per partition block (~3125)
  const int nb = (M + SCHUNK - 1) / SCHUNK;  // 49 scan blocks (must be <= 64)

  char* ws = (char*)d_ws;
  size_t off = 0;
  auto alloc = [&](size_t bytes) {
    void* p = ws + off;
    off += (bytes + 255) & ~(size_t)255;
    return p;
  };
  unsigned* featb   = (unsigned*)alloc((size_t)N * 128 * 2);
  float* el         = (float*)alloc((size_t)N * 4 * 4);
  float* er         = (float*)alloc((size_t)N * 4 * 4);
  int*   hist       = (int*)alloc((size_t)M * 4);
  int*   hscan      = (int*)alloc((size_t)(M + 1) * 4);
  int*   node_offs  = (int*)alloc((size_t)(N + 1) * 4);
  int*   blk_sums   = (int*)alloc(256);
  unsigned* part    = (unsigned*)alloc((size_t)E * 4);
  unsigned* csr     = (unsigned*)alloc((size_t)E * 4);
  uint2* wsb        = (uint2*)alloc((size_t)E * 8);

  const int G = (N + 127) / 128;  // 782 gemm blocks (128 rows each)
  gemm_hist<<<G + PB, 512, 0, stream>>>(x, fc_w, attn_l, attn_r, dst, featb,
                                        el, er, hist, N, E, NB, chunk, G);
  scan_a<<<nb, 256, 0, stream>>>(hist, hscan, blk_sums, M);
  part_scatter<<<PB, 512, 0, stream>>>(src, dst, hscan, blk_sums, part, E,
                                       NB, chunk, nb);
  build_csr<<<NB, 512, 0, stream>>>(part, hscan, blk_sums, el, er, node_offs,
                                    csr, wsb, N, E, NB, nb);
  agg_kernel<<<(N + 3) / 4, 256, 0, stream>>>((const uint4*)featb, csr,
                                              (const unsigned short*)wsb, x,
                                              bias, node_offs, out, N, E);
}